// Round 10
// baseline (112.609 us; speedup 1.0000x reference)
//
#include <hip/hip_runtime.h>

static constexpr int BB = 16;
static constexpr int NN = 256;
static constexpr int DD = 128;

__device__ __forceinline__ float sigterm(float kv, float q, float we) {
    // we * sigmoid(k+q) with ek=exp(-k), eq=exp(-q) precomputed:
    // sigmoid = 1/(1 + ek*eq)
    return we * __builtin_amdgcn_rcpf(fmaf(kv, q, 1.0f));
}

// Tiled GEMM: out[b,r,e] = sum_d x[b,r,d]*W[e,d] (+bias; exp(-.) for q,k).
// grid = 3m * 16b * 8 row-tiles * 2 e-halves = 768 blocks (3/CU), 512 thr.
// W e-half staged ROW-MAJOR with XOR swizzle (staging = b128 writes, compute
// reads 2-way aliased = free). x staged padded. LDS 48.5KB -> 3 blocks/CU.
__global__ __launch_bounds__(512) void qkv_kernel(
    const float* __restrict__ x,
    const float* __restrict__ Wq, const float* __restrict__ bq,
    const float* __restrict__ Wk, const float* __restrict__ Wv,
    float* __restrict__ eq, float* __restrict__ ek, float* __restrict__ vv)
{
    __shared__ float wlds[64 * DD];     // 64 e-rows x 128 d, swizzled (32KB)
    __shared__ float xlds[32][132];     // 32 rows x 128 d, padded (16.9KB)

    const int bid  = blockIdx.x;
    const int m    = bid % 3;                  // uniform per block
    const int rest = bid / 3;                  // 0..255
    const int eh   = rest & 1;                 // e-half
    const int tile = rest >> 1;                // 0..127
    const int b    = tile >> 3;
    const int r0   = (tile & 7) << 5;          // 32-row tile
    const int t    = threadIdx.x;

    const float* W = (m == 0) ? Wq : (m == 1) ? Wk : Wv;
    float*      op = (m == 0) ? eq : (m == 1) ? ek : vv;

    char* wb = (char*)wlds;
    {
        const float4* wg = (const float4*)(W + (size_t)(eh * 64) * DD);
        #pragma unroll
        for (int rep = 0; rep < 4; ++rep) {
            const int idx = t + (rep << 9);    // 0..2047
            const int e   = idx >> 5;          // local e row 0..63
            const int c   = idx & 31;          // 16B col
            const int byte = e * 512 + c * 16;
            *(float4*)(wb + (byte ^ (((e >> 2) & 7) << 4))) = wg[idx];
        }
        const float4* xg = (const float4*)(x + ((size_t)(b * NN + r0)) * DD);
        #pragma unroll
        for (int rep = 0; rep < 2; ++rep) {
            const int idx = t + (rep << 9);    // 0..1023
            *(float4*)&xlds[idx >> 5][(idx & 31) << 2] = xg[idx];
        }
    }
    __syncthreads();

    // thread = 1 row (rg) x 4 e (er*4..+3, within half)
    const int er = t & 15;
    const int rg = t >> 4;
    float4 acc = {0.f, 0.f, 0.f, 0.f};
    #pragma unroll 8
    for (int d4 = 0; d4 < DD / 4; ++d4) {
        const float4 xv = *(const float4*)&xlds[rg][d4 << 2];   // broadcast
        float4 w4[4];
        #pragma unroll
        for (int cc = 0; cc < 4; ++cc) {
            const int e = er * 4 + cc;
            const int byte = e * 512 + d4 * 16;
            w4[cc] = *(const float4*)(wb + (byte ^ (((e >> 2) & 7) << 4)));
        }
        acc.x = fmaf(xv.x, w4[0].x, fmaf(xv.y, w4[0].y, fmaf(xv.z, w4[0].z, fmaf(xv.w, w4[0].w, acc.x))));
        acc.y = fmaf(xv.x, w4[1].x, fmaf(xv.y, w4[1].y, fmaf(xv.z, w4[1].z, fmaf(xv.w, w4[1].w, acc.y))));
        acc.z = fmaf(xv.x, w4[2].x, fmaf(xv.y, w4[2].y, fmaf(xv.z, w4[2].z, fmaf(xv.w, w4[2].w, acc.z))));
        acc.w = fmaf(xv.x, w4[3].x, fmaf(xv.y, w4[3].y, fmaf(xv.z, w4[3].z, fmaf(xv.w, w4[3].w, acc.w))));
    }

    const int eg = eh * 64 + er * 4;           // global e base
    float4 o = acc;
    if (m == 0) {
        const float4 b4 = *(const float4*)(bq + eg);
        o.x = __expf(-(o.x + b4.x)); o.y = __expf(-(o.y + b4.y));
        o.z = __expf(-(o.z + b4.z)); o.w = __expf(-(o.w + b4.w));
    } else if (m == 1) {
        o.x = __expf(-o.x); o.y = __expf(-o.y);
        o.z = __expf(-o.z); o.w = __expf(-o.w);
    }
    *(float4*)(op + ((size_t)(b * NN + r0 + rg)) * DD + eg) = o;
}

// grid = 16 b * 32 j-tiles = 512 blocks, 512 threads, 8 j per block.
// LDS 46.9KB -> 3 blocks/CU (24 waves/CU). No Phase-D reduce: thread owns
// (j, d-pair) and accumulates over all 256 i from LDS-staged v chunks.
// Phase B: s[i][j] = edge ? sum_d We_d/(1+ek[i,d]*eq[j,d]) : 0.5*sum(We)
__global__ __launch_bounds__(512, 4) void attn_kernel(
    const int* __restrict__ A, const float* __restrict__ We,
    const float* __restrict__ eq, const float* __restrict__ ek,
    const float* __restrict__ vv, float* __restrict__ out)
{
    __shared__ float vs[64][132];    // v chunk (33792 B)
    __shared__ float eqs[8][132];    // 4224 B
    __shared__ float wes[DD];        // 512 B
    __shared__ float ssm[8][260];    // 8320 B
    __shared__ float smC;

    // bijective XCD swizzle: 512 wgs / 8 XCDs = 64 contiguous per XCD
    const int bid = (int)((blockIdx.x & 7) * 64 + (blockIdx.x >> 3));
    const int b  = bid >> 5;
    const int j0 = (bid & 31) << 3;
    const int t  = threadIdx.x;

    // ---- Phase A: stage 8 q-rows + We; wave 7 computes C = 0.5*sum(We) ----
    if (t < 256) {
        const int row = t >> 5, col = (t & 31) << 2;
        *(float4*)&eqs[row][col] =
            *(const float4*)(eq + ((size_t)(b * NN + j0 + row)) * DD + col);
    } else if (t < 288) {
        const int l = t - 256;
        *(float4*)&wes[l << 2] = ((const float4*)We)[l];
    } else if (t >= 448) {
        const int lane = t - 448;
        float w = We[lane] + We[lane + 64];
        #pragma unroll
        for (int o = 32; o > 0; o >>= 1) w += __shfl_xor(w, o);
        if (lane == 0) smC = 0.5f * w;
    }
    __syncthreads();

    // ---- Phase B: thread = (i, 4 j's). All LDS reads broadcast/2-way. ----
    {
        const float C = smC;
        const int i  = t >> 1;
        const int jh = (t & 1) << 2;     // j = jh..jh+3
        const float4* ekr = (const float4*)(ek + ((size_t)(b * NN + i)) * DD);
        const int4 a4 = *(const int4*)(A + ((size_t)(b * NN + i)) * NN + j0 + jh);
        float acc0 = 0.f, acc1 = 0.f, acc2 = 0.f, acc3 = 0.f;
        #pragma unroll 4
        for (int d4 = 0; d4 < DD / 4; ++d4) {
            const float4 kv = ekr[d4];
            const float4 we = *(const float4*)&wes[d4 << 2];
            const float4 q0 = *(const float4*)&eqs[jh + 0][d4 << 2];
            const float4 q1 = *(const float4*)&eqs[jh + 1][d4 << 2];
            const float4 q2 = *(const float4*)&eqs[jh + 2][d4 << 2];
            const float4 q3 = *(const float4*)&eqs[jh + 3][d4 << 2];
            acc0 += sigterm(kv.x, q0.x, we.x) + sigterm(kv.y, q0.y, we.y)
                  + sigterm(kv.z, q0.z, we.z) + sigterm(kv.w, q0.w, we.w);
            acc1 += sigterm(kv.x, q1.x, we.x) + sigterm(kv.y, q1.y, we.y)
                  + sigterm(kv.z, q1.z, we.z) + sigterm(kv.w, q1.w, we.w);
            acc2 += sigterm(kv.x, q2.x, we.x) + sigterm(kv.y, q2.y, we.y)
                  + sigterm(kv.z, q2.z, we.z) + sigterm(kv.w, q2.w, we.w);
            acc3 += sigterm(kv.x, q3.x, we.x) + sigterm(kv.y, q3.y, we.y)
                  + sigterm(kv.z, q3.z, we.z) + sigterm(kv.w, q3.w, we.w);
        }
        ssm[jh + 0][i] = (a4.x == 1) ? acc0 : C;
        ssm[jh + 1][i] = (a4.y == 1) ? acc1 : C;
        ssm[jh + 2][i] = (a4.z == 1) ? acc2 : C;
        ssm[jh + 3][i] = (a4.w == 1) ? acc3 : C;
    }
    __syncthreads();

    // ---- Phase C: softmax over i; wave w handles j=w (full-wave reduce) ----
    {
        const int j = t >> 6, c = t & 63;
        float vals[4];
        float mx = -1e30f;
        #pragma unroll
        for (int u = 0; u < 4; ++u) { vals[u] = ssm[j][c + (u << 6)]; mx = fmaxf(mx, vals[u]); }
        #pragma unroll
        for (int o = 32; o > 0; o >>= 1) mx = fmaxf(mx, __shfl_xor(mx, o));
        float sum = 0.0f;
        #pragma unroll
        for (int u = 0; u < 4; ++u) { vals[u] = __expf(vals[u] - mx); sum += vals[u]; }
        #pragma unroll
        for (int o = 32; o > 0; o >>= 1) sum += __shfl_xor(sum, o);
        const float inv = __builtin_amdgcn_rcpf(sum);
        #pragma unroll
        for (int u = 0; u < 4; ++u) ssm[j][c + (u << 6)] = vals[u] * inv;
    }

    // ---- Phase D: thread = (j = t>>6, d-pair = t&63); no reduce needed ----
    const int jd = t >> 6, dp = t & 63;
    float o0 = 0.f, o1 = 0.f;
    for (int ch = 0; ch < 4; ++ch) {
        __syncthreads();     // ssm ready (ch=0) / prior vs reads done (ch>0)
        const float4* vg = (const float4*)(vv + ((size_t)(b * NN) + (ch << 6)) * DD);
        #pragma unroll
        for (int rep = 0; rep < 4; ++rep) {
            const int f = t + (rep << 9);       // 0..2047
            *(float4*)&vs[f >> 5][(f & 31) << 2] = vg[f];
        }
        __syncthreads();
        #pragma unroll 8
        for (int il = 0; il < 64; ++il) {
            const float a = ssm[jd][(ch << 6) + il];          // broadcast
            const float2 v2 = *(const float2*)&vs[il][dp << 1]; // conflict-free
            o0 = fmaf(a, v2.x, o0);
            o1 = fmaf(a, v2.y, o1);
        }
    }
    *(float2*)&out[((size_t)(b * NN) + j0 + jd) * DD + (dp << 1)] = make_float2(o0, o1);
}

extern "C" void kernel_launch(void* const* d_in, const int* in_sizes, int n_in,
                              void* d_out, int out_size, void* d_ws, size_t ws_size,
                              hipStream_t stream)
{
    const float* x  = (const float*)d_in[0];
    const int*   A  = (const int*)  d_in[1];
    const float* Wq = (const float*)d_in[2];
    const float* bq = (const float*)d_in[3];
    const float* Wk = (const float*)d_in[4];
    const float* Wv = (const float*)d_in[5];
    const float* We = (const float*)d_in[6];
    float* out = (float*)d_out;

    float* eq = (float*)d_ws;
    float* ek = eq + (size_t)BB * NN * DD;
    float* vv = ek + (size_t)BB * NN * DD;

    qkv_kernel<<<3 * BB * 8 * 2, 512, 0, stream>>>(x, Wq, bq, Wk, Wv, eq, ek, vv);
    attn_kernel<<<BB * (NN / 8), 512, 0, stream>>>(A, We, eq, ek, vv, out);
}